// Round 10
// baseline (298.065 us; speedup 1.0000x reference)
//
#include <hip/hip_runtime.h>

// Problem constants: b=16, c=128, groups=8, h=w=64 -> n=4096
#define NB   16
#define NC   128
#define NPOS 4096

typedef short bf16x8 __attribute__((ext_vector_type(8)));   // 8 bf16 (4 VGPRs)
typedef float f32x4  __attribute__((ext_vector_type(4)));
typedef float f32x16 __attribute__((ext_vector_type(16)));
typedef unsigned int u32x4 __attribute__((ext_vector_type(4)));
typedef unsigned int u32x2 __attribute__((ext_vector_type(2)));

// softmax scale folded into q at QKV time: log2(e)/sqrt(128)
#define SCF 0.12751743075095855f

static __device__ __forceinline__ unsigned short f2bf(float f) {
    unsigned int u = __builtin_bit_cast(unsigned int, f);
    u += 0x7FFFu + ((u >> 16) & 1u);   // round-to-nearest-even
    return (unsigned short)(u >> 16);
}

// pack two floats -> bf16x2 dword (truncating; self-consistent softmax ratio cancels scale)
static __device__ __forceinline__ unsigned int pkbf(float hi, float lo) {
    return __builtin_amdgcn_perm(__builtin_bit_cast(unsigned int, hi),
                                 __builtin_bit_cast(unsigned int, lo), 0x07060302u);
}

// Build two B-operand frags (chunk parity 0/1) from 16 per-lane floats in C-layout.
// T12: v_permlane32_swap(A,B) -> {[A_lo|B_lo],[A_hi|B_hi]} (HW-verified R9).
static __device__ __forceinline__ void mk_bfrag_pair(const float* pp, bf16x8* dst) {
    #pragma unroll
    for (int c2 = 0; c2 < 2; ++c2) {
        int rb = c2 * 8;
        unsigned int A0 = pkbf(pp[rb + 1], pp[rb + 0]);
        unsigned int A1 = pkbf(pp[rb + 3], pp[rb + 2]);
        unsigned int B0 = pkbf(pp[rb + 5], pp[rb + 4]);
        unsigned int B1 = pkbf(pp[rb + 7], pp[rb + 6]);
        u32x2 r0 = __builtin_amdgcn_permlane32_swap(A0, B0, false, false);
        u32x2 r1 = __builtin_amdgcn_permlane32_swap(A1, B1, false, false);
        u32x4 f;
        f[0] = r0[0]; f[1] = r1[0]; f[2] = r0[1]; f[3] = r1[1];
        dst[c2] = __builtin_bit_cast(bf16x8, f);
    }
}

// Stage one 16KB frag-linear tile (8192 bf16) global -> LDS, 256 threads cooperative.
static __device__ __forceinline__ void stage_tile(unsigned short* lds, const unsigned short* g,
                                                  int t, int w) {
    #pragma unroll
    for (int c = 0; c < 4; ++c) {
        __builtin_amdgcn_global_load_lds(
            (const __attribute__((address_space(1))) unsigned int*)(g + c * 2048 + t * 8),
            (__attribute__((address_space(3))) unsigned int*)(lds + c * 2048 + w * 512),
            16, 0, 0);
    }
}

// ---------------- K0: fp32 -> bf16 weight conversion (64 blocks x 256) ----------------
__global__ void wconv_kernel(const float* __restrict__ wq, const float* __restrict__ wk,
                             const float* __restrict__ wv, const float* __restrict__ wf,
                             unsigned short* __restrict__ oq, unsigned short* __restrict__ ok,
                             unsigned short* __restrict__ ov, unsigned short* __restrict__ of) {
    int i = blockIdx.x * 256 + threadIdx.x;
    oq[i] = f2bf(wq[i]); ok[i] = f2bf(wk[i]); ov[i] = f2bf(wv[i]); of[i] = f2bf(wf[i]);
}

// ---------------- K1: GroupNorm stats, one block per (b,g), 128 blocks ----------------
__global__ void gnstat_kernel(const float* __restrict__ x, float* __restrict__ mean,
                              float* __restrict__ rstd) {
    int bg = blockIdx.x;
    const float* p = x + (size_t)bg * 65536;
    int t = threadIdx.x;
    float s = 0.f, q = 0.f;
    for (int it = 0; it < 64; ++it) {
        f32x4 v = *(const f32x4*)(p + it * 1024 + t * 4);
        s += v[0] + v[1] + v[2] + v[3];
        q += v[0] * v[0] + v[1] * v[1] + v[2] * v[2] + v[3] * v[3];
    }
    for (int m = 1; m < 64; m <<= 1) { s += __shfl_xor(s, m); q += __shfl_xor(q, m); }
    __shared__ float ls[4], lq[4];
    int w = t >> 6;
    if ((t & 63) == 0) { ls[w] = s; lq[w] = q; }
    __syncthreads();
    if (t == 0) {
        s = ls[0] + ls[1] + ls[2] + ls[3];
        q = lq[0] + lq[1] + lq[2] + lq[3];
        float mu  = s * (1.0f / 65536.0f);
        float var = q * (1.0f / 65536.0f) - mu * mu;
        mean[bg] = mu;
        rstd[bg] = rsqrtf(var + 1e-5f);
    }
}

// ---------------- K2: GN-apply + QKV GEMMs (grid 64 x 16, 256 thr) ----------------
// q pre-scaled by SCF. Outputs:
//   qT [b][n][c] row-major
//   Kf frag-linear: [b][jt][jtile*8+kc][lane=h*32+il][e] , elem K[jt*64+jtile*32+il][kc*16+h*8+e]
//   Vf frag-linear: [b][jt][ct*4+kc2][lane=h*32+il][e]   , elem V[c=ct*32+il][jt*64+kc2*16+h*8+e]
__global__ __launch_bounds__(256) void qkv_kernel(
    const float* __restrict__ x, const float* __restrict__ gnw, const float* __restrict__ gnb,
    const float* __restrict__ mean, const float* __restrict__ rstd,
    const unsigned short* __restrict__ wqb, const unsigned short* __restrict__ wkb,
    const unsigned short* __restrict__ wvb,
    const float* __restrict__ bq, const float* __restrict__ bk, const float* __restrict__ bv,
    unsigned short* __restrict__ qT, unsigned short* __restrict__ Kf, unsigned short* __restrict__ Vf) {
    __shared__ __attribute__((aligned(16))) unsigned short xn[64 * 136];  // [i][c], stride 136
    __shared__ __attribute__((aligned(16))) unsigned short bnc[64 * 128]; // bounce (8192 elems)
    const int b = blockIdx.y, i0 = blockIdx.x * 64, jt = blockIdx.x;
    const int t = threadIdx.x;
    {
        int iL = (t & 15) * 4;
        int cb = (t >> 4) * 2;
        for (int cg = 0; cg < 4; ++cg) {
            int c = cg * 32 + cb;
            int g = c >> 4;
            float mu = mean[b * 8 + g], rs = rstd[b * 8 + g];
            float ga0 = gnw[c] * rs,     be0 = gnb[c]     - mu * ga0;
            float ga1 = gnw[c + 1] * rs, be1 = gnb[c + 1] - mu * ga1;
            const float* p0 = x + ((size_t)(b * NC + c)) * NPOS + i0 + iL;
            f32x4 v0 = *(const f32x4*)p0;
            f32x4 v1 = *(const f32x4*)(p0 + NPOS);
            for (int e = 0; e < 4; ++e) {
                unsigned int u = (unsigned)f2bf(v0[e] * ga0 + be0) |
                                 ((unsigned)f2bf(v1[e] * ga1 + be1) << 16);
                *(unsigned int*)&xn[(iL + e) * 136 + c] = u;
            }
        }
    }
    __syncthreads();

    const int lane = t & 63, w = t >> 6, quad = lane >> 4, li = lane & 15;

    bf16x8 ax[4];
    for (int kc = 0; kc < 4; ++kc)
        ax[kc] = *(const bf16x8*)&xn[(w * 16 + li) * 136 + kc * 32 + quad * 8];

    // ---- q and k GEMMs; D[i][o], i = w*16+quad*4+rr, o = nt*16+li
    for (int wt = 0; wt < 2; ++wt) {
        const unsigned short* W = wt ? wkb : wqb;
        const float* bias = wt ? bk : bq;
        const float osc = wt ? 1.0f : SCF;
        for (int nt = 0; nt < 8; ++nt) {
            f32x4 d = {0.f, 0.f, 0.f, 0.f};
            for (int kc = 0; kc < 4; ++kc) {
                bf16x8 bw = *(const bf16x8*)&W[(nt * 16 + li) * 128 + kc * 32 + quad * 8];
                d = __builtin_amdgcn_mfma_f32_16x16x32_bf16(ax[kc], bw, d, 0, 0, 0);
            }
            float bb = bias[nt * 16 + li];
            int o = nt * 16 + li;
            for (int rr = 0; rr < 4; ++rr) {
                int i = w * 16 + quad * 4 + rr;
                bnc[i * 128 + (((o >> 3) ^ (i & 7)) << 3) + (o & 7)] = f2bf((d[rr] + bb) * osc);
            }
        }
        __syncthreads();
        if (wt == 0) {
            unsigned short* dst = qT + ((size_t)b * NPOS + i0) * NC + t * 32;
            int i = t >> 2;
            for (int s = 0; s < 4; ++s) {
                int cc = (t & 3) * 4 + s;
                *(bf16x8*)(dst + s * 8) = *(const bf16x8*)&bnc[i * 128 + ((cc ^ (i & 7)) << 3)];
            }
        } else {
            unsigned short* dst = Kf + ((size_t)(b * 64 + jt)) * 8192 + t * 32;
            int F = t >> 4, jtile = F >> 3, kc = F & 7;
            for (int s = 0; s < 4; ++s) {
                int L = (t * 4 + s) & 63;
                int i = jtile * 32 + (L & 31);
                int cc = kc * 2 + (L >> 5);
                *(bf16x8*)(dst + s * 8) = *(const bf16x8*)&bnc[i * 128 + ((cc ^ (i & 7)) << 3)];
            }
        }
        __syncthreads();
    }

    // ---- v GEMM: D[o=c][i=j], c = (w*2+mt)*16+quad*4+rr, j = nt*16+li
    bf16x8 av[2][4];
    for (int mt = 0; mt < 2; ++mt)
        for (int kc = 0; kc < 4; ++kc)
            av[mt][kc] = *(const bf16x8*)&wvb[((w * 2 + mt) * 16 + li) * 128 + kc * 32 + quad * 8];
    for (int nt = 0; nt < 4; ++nt) {
        bf16x8 bx[4];
        for (int kc = 0; kc < 4; ++kc)
            bx[kc] = *(const bf16x8*)&xn[(nt * 16 + li) * 136 + kc * 32 + quad * 8];
        for (int mt = 0; mt < 2; ++mt) {
            f32x4 d = {0.f, 0.f, 0.f, 0.f};
            for (int kc = 0; kc < 4; ++kc)
                d = __builtin_amdgcn_mfma_f32_16x16x32_bf16(av[mt][kc], bx[kc], d, 0, 0, 0);
            int o0 = (w * 2 + mt) * 16 + quad * 4;
            int j = nt * 16 + li;
            for (int rr = 0; rr < 4; ++rr) {
                int c = o0 + rr;
                bnc[c * 64 + (((j >> 3) ^ (c & 7)) << 3) + (j & 7)] = f2bf(d[rr] + bv[c]);
            }
        }
    }
    __syncthreads();
    {
        unsigned short* dst = Vf + ((size_t)(b * 64 + jt)) * 8192 + t * 32;
        int F = t >> 4, ct = F >> 2, kc2 = F & 3;
        for (int s = 0; s < 4; ++s) {
            int L = (t * 4 + s) & 63;
            int c = ct * 32 + (L & 31);
            int jc = kc2 * 2 + (L >> 5);
            *(bf16x8*)(dst + s * 8) = *(const bf16x8*)&bnc[c * 64 + ((jc ^ (c & 7)) << 3)];
        }
    }
}

// ---------------- flash iteration body ----------------
// QK[jt+1]-FIRST schedule: the 32 QK MFMAs (dep only on LDS staged at jt-1) issue before
// the softmax VALU of tile jt -> matrix pipe stays fed while this wave's VALU runs
// (no co-resident wave needed at 1 wave/SIMD). st double-buffered (stC current / stN next).
static __device__ __forceinline__ void flash_iter(
    int jt, f32x16 (&stC)[4], f32x16 (&stN)[4], const f32x16& z16,
    const bf16x8 (&qb)[2][8], const bf16x8& ones,
    f32x16 (&acc)[2][4], f32x16 (&accl)[2],
    unsigned short (*Kv)[8192], unsigned short (*Vv)[8192],
    const unsigned short* Kb, const unsigned short* Vb, int t, int w, int lane) {
    // staging issues first: land by this iter's end barrier.
    if (jt < 62) stage_tile(&Kv[jt & 1][0], Kb + (size_t)(jt + 2) * 8192, t, w);
    if (jt < 63) stage_tile(&Vv[(jt + 1) & 1][0], Vb + (size_t)(jt + 1) * 8192, t, w);

    const unsigned short* kl = &Kv[(jt + 1) & 1][0] + lane * 8;
    const unsigned short* vl = &Vv[jt & 1][0] + lane * 8;

    // QK[jt+1]: 16 K-frag reads feed 32 MFMAs (2 ig groups). C=z16 on kc==0 (no re-zeroing).
    // At jt=63 this reads stale-but-valid LDS (Kv[0]=K[62]); stN then discarded.
    __builtin_amdgcn_s_setprio(1);
    #pragma unroll
    for (int kc = 0; kc < 8; ++kc) {
        bf16x8 k0 = *(const bf16x8*)(kl + kc * 512);
        bf16x8 k1 = *(const bf16x8*)(kl + (8 + kc) * 512);
        stN[0] = __builtin_amdgcn_mfma_f32_32x32x16_bf16(k0, qb[0][kc], kc ? stN[0] : z16, 0, 0, 0);
        stN[1] = __builtin_amdgcn_mfma_f32_32x32x16_bf16(k1, qb[0][kc], kc ? stN[1] : z16, 0, 0, 0);
        stN[2] = __builtin_amdgcn_mfma_f32_32x32x16_bf16(k0, qb[1][kc], kc ? stN[2] : z16, 0, 0, 0);
        stN[3] = __builtin_amdgcn_mfma_f32_32x32x16_bf16(k1, qb[1][kc], kc ? stN[3] : z16, 0, 0, 0);
    }
    __builtin_amdgcn_s_setprio(0);

    // softmax of tile jt (no max-tracking, no centering; scale cancels in ratio) —
    // VALU runs while the matrix pipe chews the QK cluster above.
    #pragma unroll
    for (int u = 0; u < 4; ++u)
        #pragma unroll
        for (int q = 0; q < 16; ++q) stC[u][q] = __builtin_amdgcn_exp2f(stC[u][q]);

    bf16x8 pfrag[2][4];
    mk_bfrag_pair((const float*)&stC[0], &pfrag[0][0]);
    mk_bfrag_pair((const float*)&stC[1], &pfrag[0][2]);
    mk_bfrag_pair((const float*)&stC[2], &pfrag[1][0]);
    mk_bfrag_pair((const float*)&stC[3], &pfrag[1][2]);

    // PV + rowsum: 16 V-frag reads feed 32 PV MFMAs (2 ig) + 8 ones-MFMA rowsums.
    __builtin_amdgcn_s_setprio(1);
    #pragma unroll
    for (int i = 0; i < 16; ++i) {
        const int ct = i & 3, kc2 = i >> 2;
        bf16x8 vfm = *(const bf16x8*)(vl + (ct * 4 + kc2) * 512);
        acc[0][ct] = __builtin_amdgcn_mfma_f32_32x32x16_bf16(vfm, pfrag[0][kc2], acc[0][ct], 0, 0, 0);
        acc[1][ct] = __builtin_amdgcn_mfma_f32_32x32x16_bf16(vfm, pfrag[1][kc2], acc[1][ct], 0, 0, 0);
        if ((i & 3) == 3) {
            accl[0] = __builtin_amdgcn_mfma_f32_32x32x16_bf16(ones, pfrag[0][i >> 2], accl[0], 0, 0, 0);
            accl[1] = __builtin_amdgcn_mfma_f32_32x32x16_bf16(ones, pfrag[1][i >> 2], accl[1], 0, 0, 0);
        }
    }
    __builtin_amdgcn_s_setprio(0);

    // barrier: waves done reading Kv[(jt+1)&1]/Vv[jt&1]; drains vmcnt so K[jt+2]/V[jt+1]
    // staging is complete for the next iteration's reads.
    __syncthreads();
}

// ---------------- K3: flash attention + fused output projection + residual ----------------
// grid 256 x 256 thr = 4 waves/block; each wave owns 64 q-rows (2 ig groups), full j sweep.
// R10: halves LDS read traffic per FLOP vs 32-row waves (R9 was ~55% LDS-BW-busy: 256KB
// reads/CU/iter). Each K/V frag read feeds TWO MFMAs. 1 block/CU, 1 wave/SIMD; the VALU
// exposure that killed R5 at this occupancy is fixed by the QK-first schedule + st dbuf
// (R7's skew) + no max-tracking + LDS staging. Regs ~420 <= 512 @ launch_bounds(256,1).
__global__ __launch_bounds__(256, 1) void flash_kernel(
    const unsigned short* __restrict__ qT, const unsigned short* __restrict__ Kf,
    const unsigned short* __restrict__ Vf, const unsigned short* __restrict__ wfb,
    const float* __restrict__ bf_, const float* __restrict__ x, float* __restrict__ out) {
    __shared__ __attribute__((aligned(16))) unsigned short Kv[2][8192];  // 32KB K double-buffer
    __shared__ __attribute__((aligned(16))) unsigned short Vv[2][8192];  // 32KB V double-buffer
    const int idx = blockIdx.x;
    const int b = (idx & 7) * 2 + ((idx >> 3) & 1);   // XCD x holds batches {2x,2x+1} (4MB K/V = L2)
    const int rg = idx >> 4;                          // 0..15
    const int t = threadIdx.x, lane = t & 63, w = t >> 6;
    const int il = lane & 31, h = lane >> 5;
    const int iw = (rg * 4 + w) * 64;                 // this wave's 64 q-rows

    const unsigned short* Kb = Kf + ((size_t)b * 64) * 8192;
    const unsigned short* Vb = Vf + ((size_t)b * 64) * 8192;

    // prologue: stage K0 (slot 0), K1 (slot 1), V0 (slot 0)
    stage_tile(&Kv[0][0], Kb, t, w);
    stage_tile(&Kv[1][0], Kb + 8192, t, w);
    stage_tile(&Vv[0][0], Vb, t, w);

    bf16x8 qb[2][8];
    #pragma unroll
    for (int ig = 0; ig < 2; ++ig)
        #pragma unroll
        for (int kc = 0; kc < 8; ++kc)
            qb[ig][kc] = *(const bf16x8*)&qT[((size_t)b * NPOS + iw + ig * 32 + il) * NC + kc * 16 + h * 8];

    bf16x8 ones;
    {
        u32x4 o; o[0] = o[1] = o[2] = o[3] = 0x3F803F80u;   // bf16 1.0 x8
        ones = __builtin_bit_cast(bf16x8, o);
    }
    f32x16 z16;
    #pragma unroll
    for (int q = 0; q < 16; ++q) z16[q] = 0.f;

    f32x16 acc[2][4], accl[2];
    #pragma unroll
    for (int ig = 0; ig < 2; ++ig) {
        #pragma unroll
        for (int ct = 0; ct < 4; ++ct)
            #pragma unroll
            for (int q = 0; q < 16; ++q) acc[ig][ct][q] = 0.f;
        #pragma unroll
        for (int q = 0; q < 16; ++q) accl[ig][q] = 0.f;
    }

    __syncthreads();   // K0,K1,V0 staged (barrier drains vmcnt)

    // QK[0] -> stA (skewed out of the loop)
    f32x16 stA[4], stB[4];
    {
        const unsigned short* kl = &Kv[0][0] + lane * 8;
        __builtin_amdgcn_s_setprio(1);
        #pragma unroll
        for (int kc = 0; kc < 8; ++kc) {
            bf16x8 k0 = *(const bf16x8*)(kl + kc * 512);
            bf16x8 k1 = *(const bf16x8*)(kl + (8 + kc) * 512);
            stA[0] = __builtin_amdgcn_mfma_f32_32x32x16_bf16(k0, qb[0][kc], kc ? stA[0] : z16, 0, 0, 0);
            stA[1] = __builtin_amdgcn_mfma_f32_32x32x16_bf16(k1, qb[0][kc], kc ? stA[1] : z16, 0, 0, 0);
            stA[2] = __builtin_amdgcn_mfma_f32_32x32x16_bf16(k0, qb[1][kc], kc ? stA[2] : z16, 0, 0, 0);
            stA[3] = __builtin_amdgcn_mfma_f32_32x32x16_bf16(k1, qb[1][kc], kc ? stA[3] : z16, 0, 0, 0);
        }
        __builtin_amdgcn_s_setprio(0);
    }
    __syncthreads();   // all waves done reading Kv[0] before iter 0 stages K[2] into it

    for (int jo = 0; jo < 32; ++jo) {
        flash_iter(2 * jo,     stA, stB, z16, qb, ones, acc, accl, Kv, Vv, Kb, Vb, t, w, lane);
        flash_iter(2 * jo + 1, stB, stA, z16, qb, ones, acc, accl, Kv, Vv, Kb, Vb, t, w, lane);
    }

    // ---- Epilogue: lr from accl (all C-rows equal -> lane-local), normalize O,
    // B-frags, wf proj, +bias +x, store fp32
    bf16x8 obf[2][8];
    #pragma unroll
    for (int ig = 0; ig < 2; ++ig) {
        float inv = __builtin_amdgcn_rcpf(accl[ig][0]) * 1.001953125f;  // centers O pkbf trunc
        #pragma unroll
        for (int ct = 0; ct < 4; ++ct) {
            float pp[16];
            #pragma unroll
            for (int q = 0; q < 16; ++q) pp[q] = acc[ig][ct][q] * inv;
            mk_bfrag_pair(pp, &obf[ig][ct * 2]);
        }
    }

    #pragma unroll
    for (int ot = 0; ot < 4; ++ot) {
        bf16x8 wfA[8];
        #pragma unroll
        for (int kc = 0; kc < 8; ++kc)
            wfA[kc] = *(const bf16x8*)&wfb[(ot * 32 + il) * 128 + kc * 16 + h * 8];
        #pragma unroll
        for (int ig = 0; ig < 2; ++ig) {
            f32x16 d;
            #pragma unroll
            for (int q = 0; q < 16; ++q) d[q] = 0.f;
            #pragma unroll
            for (int kc = 0; kc < 8; ++kc)
                d = __builtin_amdgcn_mfma_f32_32x32x16_bf16(wfA[kc], obf[ig][kc], d, 0, 0, 0);
            const int gi = iw + ig * 32 + il;
            #pragma unroll
            for (int q = 0; q < 16; ++q) {
                int o = ot * 32 + (q & 3) + 8 * (q >> 2) + 4 * h;
                size_t a = ((size_t)(b * NC + o)) * NPOS + gi;
                out[a] = d[q] + bf_[o] + x[a];
            }
        }
    }
}

extern "C" void kernel_launch(void* const* d_in, const int* in_sizes, int n_in,
                              void* d_out, int out_size, void* d_ws, size_t ws_size,
                              hipStream_t stream) {
    const float* x   = (const float*)d_in[0];
    const float* gnw = (const float*)d_in[1];
    const float* gnb = (const float*)d_in[2];
    const float* wq  = (const float*)d_in[3];
    const float* bq  = (const float*)d_in[4];
    const float* wk  = (const float*)d_in[5];
    const float* bk  = (const float*)d_in[6];
    const float* wv  = (const float*)d_in[7];
    const float* bv  = (const float*)d_in[8];
    const float* wf  = (const float*)d_in[9];
    const float* bf_ = (const float*)d_in[10];
    float* out = (float*)d_out;

    char* ws = (char*)d_ws;
    float* mean = (float*)(ws + 0);
    float* rstd = (float*)(ws + 512);
    unsigned short* wqb = (unsigned short*)(ws + 1024);
    unsigned short* wkb = wqb + 16384;
    unsigned short* wvb = wkb + 16384;
    unsigned short* wfb = wvb + 16384;
    unsigned short* qT  = (unsigned short*)(ws + 132096);          // [b][n][c] bf16 (SCF-scaled)
    unsigned short* Kf  = qT + (size_t)NB * NPOS * NC;             // frag-linear K
    unsigned short* Vf  = Kf + (size_t)NB * NPOS * NC;             // frag-linear V

    wconv_kernel<<<64, 256, 0, stream>>>(wq, wk, wv, wf, wqb, wkb, wvb, wfb);
    gnstat_kernel<<<128, 256, 0, stream>>>(x, mean, rstd);
    dim3 g(64, 16);
    qkv_kernel<<<g, 256, 0, stream>>>(x, gnw, gnb, mean, rstd, wqb, wkb, wvb, bq, bk, bv, qT, Kf, Vf);
    flash_kernel<<<256, 256, 0, stream>>>(qT, Kf, Vf, wfb, bf_, x, out);
}

// Round 11
// 297.992 us; speedup vs baseline: 1.0002x; 1.0002x over previous
//
#include <hip/hip_runtime.h>

// Problem constants: b=16, c=128, groups=8, h=w=64 -> n=4096
#define NB   16
#define NC   128
#define NPOS 4096

typedef short bf16x8 __attribute__((ext_vector_type(8)));   // 8 bf16 (4 VGPRs)
typedef float f32x4  __attribute__((ext_vector_type(4)));
typedef float f32x16 __attribute__((ext_vector_type(16)));
typedef unsigned int u32x4 __attribute__((ext_vector_type(4)));
typedef unsigned int u32x2 __attribute__((ext_vector_type(2)));

// softmax scale folded into q at QKV time: log2(e)/sqrt(128)
#define SCF 0.12751743075095855f

static __device__ __forceinline__ unsigned short f2bf(float f) {
    unsigned int u = __builtin_bit_cast(unsigned int, f);
    u += 0x7FFFu + ((u >> 16) & 1u);   // round-to-nearest-even
    return (unsigned short)(u >> 16);
}

// pack two floats -> bf16x2 dword (truncating; exp2-arg centering compensates)
static __device__ __forceinline__ unsigned int pkbf(float hi, float lo) {
    return __builtin_amdgcn_perm(__builtin_bit_cast(unsigned int, hi),
                                 __builtin_bit_cast(unsigned int, lo), 0x07060302u);
}

static __device__ __forceinline__ float vsum16(const float* p) {
    float a = (p[0] + p[1]) + (p[2] + p[3]);
    float b = (p[4] + p[5]) + (p[6] + p[7]);
    float c = (p[8] + p[9]) + (p[10] + p[11]);
    float d = (p[12] + p[13]) + (p[14] + p[15]);
    return (a + b) + (c + d);
}

// Build two B-operand frags (chunk parity 0/1) from 16 per-lane floats in C-layout.
// T12: v_permlane32_swap(A,B) -> {[A_lo|B_lo],[A_hi|B_hi]} (HW-verified R9).
static __device__ __forceinline__ void mk_bfrag_pair(const float* pp, bf16x8* dst) {
    #pragma unroll
    for (int c2 = 0; c2 < 2; ++c2) {
        int rb = c2 * 8;
        unsigned int A0 = pkbf(pp[rb + 1], pp[rb + 0]);
        unsigned int A1 = pkbf(pp[rb + 3], pp[rb + 2]);
        unsigned int B0 = pkbf(pp[rb + 5], pp[rb + 4]);
        unsigned int B1 = pkbf(pp[rb + 7], pp[rb + 6]);
        u32x2 r0 = __builtin_amdgcn_permlane32_swap(A0, B0, false, false);
        u32x2 r1 = __builtin_amdgcn_permlane32_swap(A1, B1, false, false);
        u32x4 f;
        f[0] = r0[0]; f[1] = r1[0]; f[2] = r0[1]; f[3] = r1[1];
        dst[c2] = __builtin_bit_cast(bf16x8, f);
    }
}

// Stage one 16KB frag-linear tile (8192 bf16) global -> LDS, 256 threads cooperative.
static __device__ __forceinline__ void stage_tile(unsigned short* lds, const unsigned short* g,
                                                  int t, int w) {
    #pragma unroll
    for (int c = 0; c < 4; ++c) {
        __builtin_amdgcn_global_load_lds(
            (const __attribute__((address_space(1))) unsigned int*)(g + c * 2048 + t * 8),
            (__attribute__((address_space(3))) unsigned int*)(lds + c * 2048 + w * 512),
            16, 0, 0);
    }
}

// ---------------- K1: GroupNorm stats + fused weight fp32->bf16 conversion ----------------
// 128 blocks x 256 thr. Weight conversion fused in (removes the old wconv launch): each
// thread converts 2 consecutive elems of the combined 4x16384 weight space (pairs never
// cross a matrix boundary since boundaries are even and pair starts are even).
__global__ void gnstat_kernel(const float* __restrict__ x, float* __restrict__ mean,
                              float* __restrict__ rstd,
                              const float* __restrict__ wq, const float* __restrict__ wk,
                              const float* __restrict__ wv, const float* __restrict__ wf,
                              unsigned short* __restrict__ oq, unsigned short* __restrict__ ok,
                              unsigned short* __restrict__ ov, unsigned short* __restrict__ of) {
    int bg = blockIdx.x;
    int t = threadIdx.x;
    {
        int e2 = (bg * 256 + t) * 2;
        int m = e2 >> 14, e = e2 & 16383;
        const float* W = m == 0 ? wq : m == 1 ? wk : m == 2 ? wv : wf;
        unsigned short* O = m == 0 ? oq : m == 1 ? ok : m == 2 ? ov : of;
        float2 v = *(const float2*)&W[e];
        O[e] = f2bf(v.x); O[e + 1] = f2bf(v.y);
    }
    const float* p = x + (size_t)bg * 65536;
    float s = 0.f, q = 0.f;
    for (int it = 0; it < 64; ++it) {
        f32x4 v = *(const f32x4*)(p + it * 1024 + t * 4);
        s += v[0] + v[1] + v[2] + v[3];
        q += v[0] * v[0] + v[1] * v[1] + v[2] * v[2] + v[3] * v[3];
    }
    for (int m = 1; m < 64; m <<= 1) { s += __shfl_xor(s, m); q += __shfl_xor(q, m); }
    __shared__ float ls[4], lq[4];
    int w = t >> 6;
    if ((t & 63) == 0) { ls[w] = s; lq[w] = q; }
    __syncthreads();
    if (t == 0) {
        s = ls[0] + ls[1] + ls[2] + ls[3];
        q = lq[0] + lq[1] + lq[2] + lq[3];
        float mu  = s * (1.0f / 65536.0f);
        float var = q * (1.0f / 65536.0f) - mu * mu;
        mean[bg] = mu;
        rstd[bg] = rsqrtf(var + 1e-5f);
    }
}

// ---------------- K2: GN-apply + QKV GEMMs (grid 64 x 16, 256 thr) ----------------
// q pre-scaled by SCF. Outputs:
//   qT [b][n][c] row-major
//   Kf frag-linear: [b][jt][jtile*8+kc][lane=h*32+il][e] , elem K[jt*64+jtile*32+il][kc*16+h*8+e]
//   Vf frag-linear: [b][jt][ct*4+kc2][lane=h*32+il][e]   , elem V[c=ct*32+il][jt*64+kc2*16+h*8+e]
__global__ __launch_bounds__(256) void qkv_kernel(
    const float* __restrict__ x, const float* __restrict__ gnw, const float* __restrict__ gnb,
    const float* __restrict__ mean, const float* __restrict__ rstd,
    const unsigned short* __restrict__ wqb, const unsigned short* __restrict__ wkb,
    const unsigned short* __restrict__ wvb,
    const float* __restrict__ bq, const float* __restrict__ bk, const float* __restrict__ bv,
    unsigned short* __restrict__ qT, unsigned short* __restrict__ Kf, unsigned short* __restrict__ Vf) {
    __shared__ __attribute__((aligned(16))) unsigned short xn[64 * 136];  // [i][c], stride 136
    __shared__ __attribute__((aligned(16))) unsigned short bnc[64 * 128]; // bounce (8192 elems)
    const int b = blockIdx.y, i0 = blockIdx.x * 64, jt = blockIdx.x;
    const int t = threadIdx.x;
    {
        int iL = (t & 15) * 4;
        int cb = (t >> 4) * 2;
        for (int cg = 0; cg < 4; ++cg) {
            int c = cg * 32 + cb;
            int g = c >> 4;
            float mu = mean[b * 8 + g], rs = rstd[b * 8 + g];
            float ga0 = gnw[c] * rs,     be0 = gnb[c]     - mu * ga0;
            float ga1 = gnw[c + 1] * rs, be1 = gnb[c + 1] - mu * ga1;
            const float* p0 = x + ((size_t)(b * NC + c)) * NPOS + i0 + iL;
            f32x4 v0 = *(const f32x4*)p0;
            f32x4 v1 = *(const f32x4*)(p0 + NPOS);
            for (int e = 0; e < 4; ++e) {
                unsigned int u = (unsigned)f2bf(v0[e] * ga0 + be0) |
                                 ((unsigned)f2bf(v1[e] * ga1 + be1) << 16);
                *(unsigned int*)&xn[(iL + e) * 136 + c] = u;
            }
        }
    }
    __syncthreads();

    const int lane = t & 63, w = t >> 6, quad = lane >> 4, li = lane & 15;

    bf16x8 ax[4];
    for (int kc = 0; kc < 4; ++kc)
        ax[kc] = *(const bf16x8*)&xn[(w * 16 + li) * 136 + kc * 32 + quad * 8];

    // ---- q and k GEMMs; D[i][o], i = w*16+quad*4+rr, o = nt*16+li
    for (int wt = 0; wt < 2; ++wt) {
        const unsigned short* W = wt ? wkb : wqb;
        const float* bias = wt ? bk : bq;
        const float osc = wt ? 1.0f : SCF;
        for (int nt = 0; nt < 8; ++nt) {
            f32x4 d = {0.f, 0.f, 0.f, 0.f};
            for (int kc = 0; kc < 4; ++kc) {
                bf16x8 bw = *(const bf16x8*)&W[(nt * 16 + li) * 128 + kc * 32 + quad * 8];
                d = __builtin_amdgcn_mfma_f32_16x16x32_bf16(ax[kc], bw, d, 0, 0, 0);
            }
            float bb = bias[nt * 16 + li];
            int o = nt * 16 + li;
            for (int rr = 0; rr < 4; ++rr) {
                int i = w * 16 + quad * 4 + rr;
                bnc[i * 128 + (((o >> 3) ^ (i & 7)) << 3) + (o & 7)] = f2bf((d[rr] + bb) * osc);
            }
        }
        __syncthreads();
        if (wt == 0) {
            unsigned short* dst = qT + ((size_t)b * NPOS + i0) * NC + t * 32;
            int i = t >> 2;
            for (int s = 0; s < 4; ++s) {
                int cc = (t & 3) * 4 + s;
                *(bf16x8*)(dst + s * 8) = *(const bf16x8*)&bnc[i * 128 + ((cc ^ (i & 7)) << 3)];
            }
        } else {
            unsigned short* dst = Kf + ((size_t)(b * 64 + jt)) * 8192 + t * 32;
            int F = t >> 4, jtile = F >> 3, kc = F & 7;
            for (int s = 0; s < 4; ++s) {
                int L = (t * 4 + s) & 63;
                int i = jtile * 32 + (L & 31);
                int cc = kc * 2 + (L >> 5);
                *(bf16x8*)(dst + s * 8) = *(const bf16x8*)&bnc[i * 128 + ((cc ^ (i & 7)) << 3)];
            }
        }
        __syncthreads();
    }

    // ---- v GEMM: D[o=c][i=j], c = (w*2+mt)*16+quad*4+rr, j = nt*16+li
    bf16x8 av[2][4];
    for (int mt = 0; mt < 2; ++mt)
        for (int kc = 0; kc < 4; ++kc)
            av[mt][kc] = *(const bf16x8*)&wvb[((w * 2 + mt) * 16 + li) * 128 + kc * 32 + quad * 8];
    for (int nt = 0; nt < 4; ++nt) {
        bf16x8 bx[4];
        for (int kc = 0; kc < 4; ++kc)
            bx[kc] = *(const bf16x8*)&xn[(nt * 16 + li) * 136 + kc * 32 + quad * 8];
        for (int mt = 0; mt < 2; ++mt) {
            f32x4 d = {0.f, 0.f, 0.f, 0.f};
            for (int kc = 0; kc < 4; ++kc)
                d = __builtin_amdgcn_mfma_f32_16x16x32_bf16(av[mt][kc], bx[kc], d, 0, 0, 0);
            int o0 = (w * 2 + mt) * 16 + quad * 4;
            int j = nt * 16 + li;
            for (int rr = 0; rr < 4; ++rr) {
                int c = o0 + rr;
                bnc[c * 64 + (((j >> 3) ^ (c & 7)) << 3) + (j & 7)] = f2bf(d[rr] + bv[c]);
            }
        }
    }
    __syncthreads();
    {
        unsigned short* dst = Vf + ((size_t)(b * 64 + jt)) * 8192 + t * 32;
        int F = t >> 4, ct = F >> 2, kc2 = F & 3;
        for (int s = 0; s < 4; ++s) {
            int L = (t * 4 + s) & 63;
            int c = ct * 32 + (L & 31);
            int jc = kc2 * 2 + (L >> 5);
            *(bf16x8*)(dst + s * 8) = *(const bf16x8*)&bnc[c * 64 + ((jc ^ (c & 7)) << 3)];
        }
    }
}

// ---------------- flash iteration body (compile-time staging/QK/barrier flags) ----------------
// R11 vs R9: rowsum moved off the matrix pipe (MFMA 36->32/iter, the hottest pipe at 49%)
// back to the VALU tree with the cross-half combine deferred to the epilogue (R8-proven
// arithmetic); st re-zeroing replaced by z16 C-operand on each QK chain's first MFMA
// (-32 v_mov/iter); last two iters peeled (branch-free hot loop, no wasted QK(64)).
template<bool SK, bool SV, bool DOQK, bool BAR>
static __device__ __forceinline__ void flash_body(
    int jt, f32x16 (&st)[2], const f32x16& z16, const bf16x8 (&qb)[8],
    f32x16 (&acc)[4], float& lr,
    unsigned short (*Kv)[8192], unsigned short (*Vv)[8192],
    const unsigned short* Kb, const unsigned short* Vb, int t, int w, int lane) {
    // staging issues first: lands by this iter's end barrier.
    if (SK) stage_tile(&Kv[jt & 1][0], Kb + (size_t)(jt + 2) * 8192, t, w);
    if (SV) stage_tile(&Vv[(jt + 1) & 1][0], Vb + (size_t)(jt + 1) * 8192, t, w);

    // softmax of tile jt (no max-tracking; +eps centers pkbf truncation, R8 arithmetic)
    #pragma unroll
    for (int q = 0; q < 16; ++q) {
        st[0][q] = __builtin_amdgcn_exp2f(st[0][q] + 0.0028150156f);
        st[1][q] = __builtin_amdgcn_exp2f(st[1][q] + 0.0028150156f);
    }
    lr += vsum16((const float*)&st[0]) + vsum16((const float*)&st[1]);  // per-half partial

    bf16x8 pfrag[4];
    mk_bfrag_pair((const float*)&st[0], &pfrag[0]);
    mk_bfrag_pair((const float*)&st[1], &pfrag[2]);

    const unsigned short* vl = &Vv[jt & 1][0] + lane * 8;
    const unsigned short* kl = &Kv[(jt + 1) & 1][0] + lane * 8;

    // ONE interleaved cluster: 4 PV chains + (optionally) 2 QK chains. QK chains start
    // from z16 C-operand on their first MFMA (i<2) -> no st re-zero pass.
    __builtin_amdgcn_s_setprio(1);
    #pragma unroll
    for (int i = 0; i < 16; ++i) {
        const int ct = i & 3, kc2 = i >> 2;          // PV chain rotates every instr
        bf16x8 vfm = *(const bf16x8*)(vl + (ct * 4 + kc2) * 512);
        acc[ct] = __builtin_amdgcn_mfma_f32_32x32x16_bf16(vfm, pfrag[kc2], acc[ct], 0, 0, 0);
        if (DOQK) {
            const int ch = i & 1, kc = i >> 1;       // QK chain alternates
            bf16x8 kx = *(const bf16x8*)(kl + (ch * 8 + kc) * 512);
            st[ch] = __builtin_amdgcn_mfma_f32_32x32x16_bf16(kx, qb[kc],
                                                             (i < 2) ? z16 : st[ch], 0, 0, 0);
        }
    }
    __builtin_amdgcn_s_setprio(0);

    // barrier: all waves done reading Kv[(jt+1)&1]/Vv[jt&1]; drains vmcnt so staged
    // K[jt+2]/V[jt+1] are complete for the next iteration's reads.
    if (BAR) __syncthreads();
}

// ---------------- K3: flash attention + fused output projection + residual ----------------
// grid 512 x 256 thr = 4 waves/block, 32 q-rows/wave, 2 blocks/CU, 2 waves/SIMD (R9 base —
// the proven optimum of the occupancy x LDS-reuse tradeoff; 64-row waves cap at 1 wave/SIMD
// and lost twice, R5/R10).
__global__ __launch_bounds__(256, 2) void flash_kernel(
    const unsigned short* __restrict__ qT, const unsigned short* __restrict__ Kf,
    const unsigned short* __restrict__ Vf, const unsigned short* __restrict__ wfb,
    const float* __restrict__ bf_, const float* __restrict__ x, float* __restrict__ out) {
    __shared__ __attribute__((aligned(16))) unsigned short Kv[2][8192];  // 32KB K double-buffer
    __shared__ __attribute__((aligned(16))) unsigned short Vv[2][8192];  // 32KB V double-buffer
    const int idx = blockIdx.x;
    const int b = (idx & 7) * 2 + ((idx >> 3) & 1);   // XCD x holds batches {2x,2x+1} (4MB K/V = L2)
    const int rg = idx >> 4;                          // 0..31
    const int t = threadIdx.x, lane = t & 63, w = t >> 6;
    const int il = lane & 31, h = lane >> 5;
    const int iw = (rg * 4 + w) * 32;                 // this wave's 32 q-rows

    const unsigned short* Kb = Kf + ((size_t)b * 64) * 8192;
    const unsigned short* Vb = Vf + ((size_t)b * 64) * 8192;

    // prologue: stage K0 (slot 0), K1 (slot 1), V0 (slot 0)
    stage_tile(&Kv[0][0], Kb, t, w);
    stage_tile(&Kv[1][0], Kb + 8192, t, w);
    stage_tile(&Vv[0][0], Vb, t, w);

    bf16x8 qb[8];
    #pragma unroll
    for (int kc = 0; kc < 8; ++kc)
        qb[kc] = *(const bf16x8*)&qT[((size_t)b * NPOS + iw + il) * NC + kc * 16 + h * 8];

    f32x16 z16;
    #pragma unroll
    for (int q = 0; q < 16; ++q) z16[q] = 0.f;

    float lr = 0.f;
    f32x16 acc[4];
    #pragma unroll
    for (int ct = 0; ct < 4; ++ct)
        #pragma unroll
        for (int q = 0; q < 16; ++q) acc[ct][q] = 0.f;

    __syncthreads();   // K0,K1,V0 staged (barrier drains vmcnt)

    // QK[0] (skewed out of the loop; z16 C-operand on first MFMA of each chain)
    f32x16 st[2];
    {
        const unsigned short* kl = &Kv[0][0] + lane * 8;
        __builtin_amdgcn_s_setprio(1);
        #pragma unroll
        for (int kc = 0; kc < 8; ++kc) {
            bf16x8 k0 = *(const bf16x8*)(kl + kc * 512);
            bf16x8 k1 = *(const bf16x8*)(kl + (8 + kc) * 512);
            st[0] = __builtin_amdgcn_mfma_f32_32x32x16_bf16(k0, qb[kc], kc ? st[0] : z16, 0, 0, 0);
            st[1] = __builtin_amdgcn_mfma_f32_32x32x16_bf16(k1, qb[kc], kc ? st[1] : z16, 0, 0, 0);
        }
        __builtin_amdgcn_s_setprio(0);
    }
    __syncthreads();   // all waves done reading Kv[0] before iter 0 stages K[2] into it

    // hot loop branch-free (stage K[jt+2] valid for jt<=61, V[jt+1] for jt<=62)
    for (int jt = 0; jt < 62; ++jt)
        flash_body<true, true, true, true>(jt, st, z16, qb, acc, lr, Kv, Vv, Kb, Vb, t, w, lane);
    flash_body<false, true, true, true>(62, st, z16, qb, acc, lr, Kv, Vv, Kb, Vb, t, w, lane);
    flash_body<false, false, false, false>(63, st, z16, qb, acc, lr, Kv, Vv, Kb, Vb, t, w, lane);

    // ---- Epilogue: combine per-half lr, normalize O, B-frags, wf proj, +bias +x, store
    lr += __shfl_xor(lr, 32);   // deferred cross-half combine (once)
    bf16x8 obf[8];
    {
        float inv = __builtin_amdgcn_rcpf(lr) * 1.001953125f;  // centers O pkbf truncation
        #pragma unroll
        for (int ct = 0; ct < 4; ++ct) {
            float pp[16];
            #pragma unroll
            for (int q = 0; q < 16; ++q) pp[q] = acc[ct][q] * inv;
            mk_bfrag_pair(pp, &obf[ct * 2]);
        }
    }

    #pragma unroll
    for (int ot = 0; ot < 4; ++ot) {
        bf16x8 wfA[8];
        #pragma unroll
        for (int kc = 0; kc < 8; ++kc)
            wfA[kc] = *(const bf16x8*)&wfb[(ot * 32 + il) * 128 + kc * 16 + h * 8];
        f32x16 d;
        #pragma unroll
        for (int q = 0; q < 16; ++q) d[q] = 0.f;
        #pragma unroll
        for (int kc = 0; kc < 8; ++kc)
            d = __builtin_amdgcn_mfma_f32_32x32x16_bf16(wfA[kc], obf[kc], d, 0, 0, 0);
        const int gi = iw + il;
        #pragma unroll
        for (int q = 0; q < 16; ++q) {
            int o = ot * 32 + (q & 3) + 8 * (q >> 2) + 4 * h;
            size_t a = ((size_t)(b * NC + o)) * NPOS + gi;
            out[a] = d[q] + bf_[o] + x[a];
        }
    }
}

extern "C" void kernel_launch(void* const* d_in, const int* in_sizes, int n_in,
                              void* d_out, int out_size, void* d_ws, size_t ws_size,
                              hipStream_t stream) {
    const float* x   = (const float*)d_in[0];
    const float* gnw = (const float*)d_in[1];
    const float* gnb = (const float*)d_in[2];
    const float* wq  = (const float*)d_in[3];
    const float* bq  = (const float*)d_in[4];
    const float* wk  = (const float*)d_in[5];
    const float* bk  = (const float*)d_in[6];
    const float* wv  = (const float*)d_in[7];
    const float* bv  = (const float*)d_in[8];
    const float* wf  = (const float*)d_in[9];
    const float* bf_ = (const float*)d_in[10];
    float* out = (float*)d_out;

    char* ws = (char*)d_ws;
    float* mean = (float*)(ws + 0);
    float* rstd = (float*)(ws + 512);
    unsigned short* wqb = (unsigned short*)(ws + 1024);
    unsigned short* wkb = wqb + 16384;
    unsigned short* wvb = wkb + 16384;
    unsigned short* wfb = wvb + 16384;
    unsigned short* qT  = (unsigned short*)(ws + 132096);          // [b][n][c] bf16 (SCF-scaled)
    unsigned short* Kf  = qT + (size_t)NB * NPOS * NC;             // frag-linear K
    unsigned short* Vf  = Kf + (size_t)NB * NPOS * NC;             // frag-linear V

    gnstat_kernel<<<128, 256, 0, stream>>>(x, mean, rstd, wq, wk, wv, wf, wqb, wkb, wvb, wfb);
    dim3 g(64, 16);
    qkv_kernel<<<g, 256, 0, stream>>>(x, gnw, gnb, mean, rstd, wqb, wkb, wvb, bq, bk, bv, qT, Kf, Vf);
    flash_kernel<<<512, 256, 0, stream>>>(qT, Kf, Vf, wfb, bf_, x, out);
}

// Round 12
// 293.555 us; speedup vs baseline: 1.0154x; 1.0151x over previous
//
#include <hip/hip_runtime.h>

// Problem constants: b=16, c=128, groups=8, h=w=64 -> n=4096
#define NB   16
#define NC   128
#define NPOS 4096

typedef short bf16x8 __attribute__((ext_vector_type(8)));   // 8 bf16 (4 VGPRs)
typedef float f32x4  __attribute__((ext_vector_type(4)));
typedef float f32x16 __attribute__((ext_vector_type(16)));
typedef unsigned int u32x4 __attribute__((ext_vector_type(4)));
typedef unsigned int u32x2 __attribute__((ext_vector_type(2)));

// softmax scale folded into q at QKV time: log2(e)/sqrt(128)
#define SCF 0.12751743075095855f

static __device__ __forceinline__ unsigned short f2bf(float f) {
    unsigned int u = __builtin_bit_cast(unsigned int, f);
    u += 0x7FFFu + ((u >> 16) & 1u);   // round-to-nearest-even
    return (unsigned short)(u >> 16);
}

// pack two floats -> bf16x2 dword (truncating; self-consistent softmax ratio cancels scale)
static __device__ __forceinline__ unsigned int pkbf(float hi, float lo) {
    return __builtin_amdgcn_perm(__builtin_bit_cast(unsigned int, hi),
                                 __builtin_bit_cast(unsigned int, lo), 0x07060302u);
}

// Build two B-operand frags (chunk parity 0/1) from 16 per-lane floats in C-layout.
// T12: v_permlane32_swap(A,B) -> {[A_lo|B_lo],[A_hi|B_hi]} (HW-verified R9).
static __device__ __forceinline__ void mk_bfrag_pair(const float* pp, bf16x8* dst) {
    #pragma unroll
    for (int c2 = 0; c2 < 2; ++c2) {
        int rb = c2 * 8;
        unsigned int A0 = pkbf(pp[rb + 1], pp[rb + 0]);
        unsigned int A1 = pkbf(pp[rb + 3], pp[rb + 2]);
        unsigned int B0 = pkbf(pp[rb + 5], pp[rb + 4]);
        unsigned int B1 = pkbf(pp[rb + 7], pp[rb + 6]);
        u32x2 r0 = __builtin_amdgcn_permlane32_swap(A0, B0, false, false);
        u32x2 r1 = __builtin_amdgcn_permlane32_swap(A1, B1, false, false);
        u32x4 f;
        f[0] = r0[0]; f[1] = r1[0]; f[2] = r0[1]; f[3] = r1[1];
        dst[c2] = __builtin_bit_cast(bf16x8, f);
    }
}

// Stage one 16KB frag-linear tile (8192 bf16) global -> LDS, 256 threads cooperative.
static __device__ __forceinline__ void stage_tile(unsigned short* lds, const unsigned short* g,
                                                  int t, int w) {
    #pragma unroll
    for (int c = 0; c < 4; ++c) {
        __builtin_amdgcn_global_load_lds(
            (const __attribute__((address_space(1))) unsigned int*)(g + c * 2048 + t * 8),
            (__attribute__((address_space(3))) unsigned int*)(lds + c * 2048 + w * 512),
            16, 0, 0);
    }
}

// ---------------- K1: GroupNorm stats + fused weight fp32->bf16 conversion ----------------
// 128 blocks x 256 thr. Weight conversion fused in (removes the old wconv launch): each
// thread converts 2 consecutive elems of the combined 4x16384 weight space (pairs never
// cross a matrix boundary since boundaries are even and pair starts are even).
__global__ void gnstat_kernel(const float* __restrict__ x, float* __restrict__ mean,
                              float* __restrict__ rstd,
                              const float* __restrict__ wq, const float* __restrict__ wk,
                              const float* __restrict__ wv, const float* __restrict__ wf,
                              unsigned short* __restrict__ oq, unsigned short* __restrict__ ok,
                              unsigned short* __restrict__ ov, unsigned short* __restrict__ of) {
    int bg = blockIdx.x;
    int t = threadIdx.x;
    {
        int e2 = (bg * 256 + t) * 2;
        int m = e2 >> 14, e = e2 & 16383;
        const float* W = m == 0 ? wq : m == 1 ? wk : m == 2 ? wv : wf;
        unsigned short* O = m == 0 ? oq : m == 1 ? ok : m == 2 ? ov : of;
        float2 v = *(const float2*)&W[e];
        O[e] = f2bf(v.x); O[e + 1] = f2bf(v.y);
    }
    const float* p = x + (size_t)bg * 65536;
    float s = 0.f, q = 0.f;
    for (int it = 0; it < 64; ++it) {
        f32x4 v = *(const f32x4*)(p + it * 1024 + t * 4);
        s += v[0] + v[1] + v[2] + v[3];
        q += v[0] * v[0] + v[1] * v[1] + v[2] * v[2] + v[3] * v[3];
    }
    for (int m = 1; m < 64; m <<= 1) { s += __shfl_xor(s, m); q += __shfl_xor(q, m); }
    __shared__ float ls[4], lq[4];
    int w = t >> 6;
    if ((t & 63) == 0) { ls[w] = s; lq[w] = q; }
    __syncthreads();
    if (t == 0) {
        s = ls[0] + ls[1] + ls[2] + ls[3];
        q = lq[0] + lq[1] + lq[2] + lq[3];
        float mu  = s * (1.0f / 65536.0f);
        float var = q * (1.0f / 65536.0f) - mu * mu;
        mean[bg] = mu;
        rstd[bg] = rsqrtf(var + 1e-5f);
    }
}

// ---------------- K2: GN-apply + QKV GEMMs (grid 64 x 16, 256 thr) ----------------
// q pre-scaled by SCF. Outputs:
//   qT [b][n][c] row-major
//   Kf frag-linear: [b][jt][jtile*8+kc][lane=h*32+il][e] , elem K[jt*64+jtile*32+il][kc*16+h*8+e]
//   Vf frag-linear: [b][jt][ct*4+kc2][lane=h*32+il][e]   , elem V[c=ct*32+il][jt*64+kc2*16+h*8+e]
__global__ __launch_bounds__(256) void qkv_kernel(
    const float* __restrict__ x, const float* __restrict__ gnw, const float* __restrict__ gnb,
    const float* __restrict__ mean, const float* __restrict__ rstd,
    const unsigned short* __restrict__ wqb, const unsigned short* __restrict__ wkb,
    const unsigned short* __restrict__ wvb,
    const float* __restrict__ bq, const float* __restrict__ bk, const float* __restrict__ bv,
    unsigned short* __restrict__ qT, unsigned short* __restrict__ Kf, unsigned short* __restrict__ Vf) {
    __shared__ __attribute__((aligned(16))) unsigned short xn[64 * 136];  // [i][c], stride 136
    __shared__ __attribute__((aligned(16))) unsigned short bnc[64 * 128]; // bounce (8192 elems)
    const int b = blockIdx.y, i0 = blockIdx.x * 64, jt = blockIdx.x;
    const int t = threadIdx.x;
    {
        int iL = (t & 15) * 4;
        int cb = (t >> 4) * 2;
        for (int cg = 0; cg < 4; ++cg) {
            int c = cg * 32 + cb;
            int g = c >> 4;
            float mu = mean[b * 8 + g], rs = rstd[b * 8 + g];
            float ga0 = gnw[c] * rs,     be0 = gnb[c]     - mu * ga0;
            float ga1 = gnw[c + 1] * rs, be1 = gnb[c + 1] - mu * ga1;
            const float* p0 = x + ((size_t)(b * NC + c)) * NPOS + i0 + iL;
            f32x4 v0 = *(const f32x4*)p0;
            f32x4 v1 = *(const f32x4*)(p0 + NPOS);
            for (int e = 0; e < 4; ++e) {
                unsigned int u = (unsigned)f2bf(v0[e] * ga0 + be0) |
                                 ((unsigned)f2bf(v1[e] * ga1 + be1) << 16);
                *(unsigned int*)&xn[(iL + e) * 136 + c] = u;
            }
        }
    }
    __syncthreads();

    const int lane = t & 63, w = t >> 6, quad = lane >> 4, li = lane & 15;

    bf16x8 ax[4];
    for (int kc = 0; kc < 4; ++kc)
        ax[kc] = *(const bf16x8*)&xn[(w * 16 + li) * 136 + kc * 32 + quad * 8];

    // ---- q and k GEMMs; D[i][o], i = w*16+quad*4+rr, o = nt*16+li
    for (int wt = 0; wt < 2; ++wt) {
        const unsigned short* W = wt ? wkb : wqb;
        const float* bias = wt ? bk : bq;
        const float osc = wt ? 1.0f : SCF;
        for (int nt = 0; nt < 8; ++nt) {
            f32x4 d = {0.f, 0.f, 0.f, 0.f};
            for (int kc = 0; kc < 4; ++kc) {
                bf16x8 bw = *(const bf16x8*)&W[(nt * 16 + li) * 128 + kc * 32 + quad * 8];
                d = __builtin_amdgcn_mfma_f32_16x16x32_bf16(ax[kc], bw, d, 0, 0, 0);
            }
            float bb = bias[nt * 16 + li];
            int o = nt * 16 + li;
            for (int rr = 0; rr < 4; ++rr) {
                int i = w * 16 + quad * 4 + rr;
                bnc[i * 128 + (((o >> 3) ^ (i & 7)) << 3) + (o & 7)] = f2bf((d[rr] + bb) * osc);
            }
        }
        __syncthreads();
        if (wt == 0) {
            unsigned short* dst = qT + ((size_t)b * NPOS + i0) * NC + t * 32;
            int i = t >> 2;
            for (int s = 0; s < 4; ++s) {
                int cc = (t & 3) * 4 + s;
                *(bf16x8*)(dst + s * 8) = *(const bf16x8*)&bnc[i * 128 + ((cc ^ (i & 7)) << 3)];
            }
        } else {
            unsigned short* dst = Kf + ((size_t)(b * 64 + jt)) * 8192 + t * 32;
            int F = t >> 4, jtile = F >> 3, kc = F & 7;
            for (int s = 0; s < 4; ++s) {
                int L = (t * 4 + s) & 63;
                int i = jtile * 32 + (L & 31);
                int cc = kc * 2 + (L >> 5);
                *(bf16x8*)(dst + s * 8) = *(const bf16x8*)&bnc[i * 128 + ((cc ^ (i & 7)) << 3)];
            }
        }
        __syncthreads();
    }

    // ---- v GEMM: D[o=c][i=j], c = (w*2+mt)*16+quad*4+rr, j = nt*16+li
    bf16x8 av[2][4];
    for (int mt = 0; mt < 2; ++mt)
        for (int kc = 0; kc < 4; ++kc)
            av[mt][kc] = *(const bf16x8*)&wvb[((w * 2 + mt) * 16 + li) * 128 + kc * 32 + quad * 8];
    for (int nt = 0; nt < 4; ++nt) {
        bf16x8 bx[4];
        for (int kc = 0; kc < 4; ++kc)
            bx[kc] = *(const bf16x8*)&xn[(nt * 16 + li) * 136 + kc * 32 + quad * 8];
        for (int mt = 0; mt < 2; ++mt) {
            f32x4 d = {0.f, 0.f, 0.f, 0.f};
            for (int kc = 0; kc < 4; ++kc)
                d = __builtin_amdgcn_mfma_f32_16x16x32_bf16(av[mt][kc], bx[kc], d, 0, 0, 0);
            int o0 = (w * 2 + mt) * 16 + quad * 4;
            int j = nt * 16 + li;
            for (int rr = 0; rr < 4; ++rr) {
                int c = o0 + rr;
                bnc[c * 64 + (((j >> 3) ^ (c & 7)) << 3) + (j & 7)] = f2bf(d[rr] + bv[c]);
            }
        }
    }
    __syncthreads();
    {
        unsigned short* dst = Vf + ((size_t)(b * 64 + jt)) * 8192 + t * 32;
        int F = t >> 4, ct = F >> 2, kc2 = F & 3;
        for (int s = 0; s < 4; ++s) {
            int L = (t * 4 + s) & 63;
            int c = ct * 32 + (L & 31);
            int jc = kc2 * 2 + (L >> 5);
            *(bf16x8*)(dst + s * 8) = *(const bf16x8*)&bnc[c * 64 + ((jc ^ (c & 7)) << 3)];
        }
    }
}

// ---------------- flash iteration body (compile-time staging/QK/barrier flags) ----------------
// R12 = R9's proven body (ones-MFMA rowsum on the matrix pipe — R11 showed the VALU tree
// is WORSE; lane-local accl epilogue; no-centering self-consistent arithmetic) plus R11's
// orthogonal trims: z16 C-operand replaces the 32-v_mov st reinit, and peeled iters 62/63
// make the hot loop branch-free and drop the wasted QK(64) cluster.
template<bool SK, bool SV, bool DOQK, bool BAR>
static __device__ __forceinline__ void flash_body(
    int jt, f32x16 (&st)[2], const f32x16& z16, const bf16x8 (&qb)[8], const bf16x8& ones,
    f32x16 (&acc)[4], f32x16& accl,
    unsigned short (*Kv)[8192], unsigned short (*Vv)[8192],
    const unsigned short* Kb, const unsigned short* Vb, int t, int w, int lane) {
    // staging issues first: lands by this iter's end barrier.
    if (SK) stage_tile(&Kv[jt & 1][0], Kb + (size_t)(jt + 2) * 8192, t, w);
    if (SV) stage_tile(&Vv[(jt + 1) & 1][0], Vb + (size_t)(jt + 1) * 8192, t, w);

    // softmax of tile jt: no max-tracking, no centering (scale cancels in the
    // self-consistent ratio since lr is computed on the same truncated bf16 P)
    #pragma unroll
    for (int q = 0; q < 16; ++q) {
        st[0][q] = __builtin_amdgcn_exp2f(st[0][q]);
        st[1][q] = __builtin_amdgcn_exp2f(st[1][q]);
    }

    bf16x8 pfrag[4];
    mk_bfrag_pair((const float*)&st[0], &pfrag[0]);
    mk_bfrag_pair((const float*)&st[1], &pfrag[2]);

    const unsigned short* vl = &Vv[jt & 1][0] + lane * 8;
    const unsigned short* kl = &Kv[(jt + 1) & 1][0] + lane * 8;

    // ONE interleaved cluster: 4 PV chains + 1 rowsum chain + (optionally) 2 QK chains.
    // QK chains start from z16 C-operand on their first MFMA (i<2) -> no st re-zero pass.
    __builtin_amdgcn_s_setprio(1);
    #pragma unroll
    for (int i = 0; i < 16; ++i) {
        const int ct = i & 3, kc2 = i >> 2;          // PV chain rotates every instr
        bf16x8 vfm = *(const bf16x8*)(vl + (ct * 4 + kc2) * 512);
        acc[ct] = __builtin_amdgcn_mfma_f32_32x32x16_bf16(vfm, pfrag[kc2], acc[ct], 0, 0, 0);
        if (DOQK) {
            const int ch = i & 1, kc = i >> 1;       // QK chain alternates
            bf16x8 kx = *(const bf16x8*)(kl + (ch * 8 + kc) * 512);
            st[ch] = __builtin_amdgcn_mfma_f32_32x32x16_bf16(kx, qb[kc],
                                                             (i < 2) ? z16 : st[ch], 0, 0, 0);
        }
        if ((i & 3) == 3)                            // rowsum chain: 4 per iter (matrix pipe)
            accl = __builtin_amdgcn_mfma_f32_32x32x16_bf16(ones, pfrag[i >> 2], accl, 0, 0, 0);
    }
    __builtin_amdgcn_s_setprio(0);

    // barrier: all waves done reading Kv[(jt+1)&1]/Vv[jt&1]; drains vmcnt so staged
    // K[jt+2]/V[jt+1] are complete for the next iteration's reads.
    if (BAR) __syncthreads();
}

// ---------------- K3: flash attention + fused output projection + residual ----------------
// grid 512 x 256 thr = 4 waves/block, 32 q-rows/wave, 2 blocks/CU, 2 waves/SIMD (R9 base —
// the proven optimum of the occupancy x LDS-reuse tradeoff; 64-row waves cap at 1 wave/SIMD
// and lost twice, R5/R10; rowsum-on-VALU lost once, R11).
__global__ __launch_bounds__(256, 2) void flash_kernel(
    const unsigned short* __restrict__ qT, const unsigned short* __restrict__ Kf,
    const unsigned short* __restrict__ Vf, const unsigned short* __restrict__ wfb,
    const float* __restrict__ bf_, const float* __restrict__ x, float* __restrict__ out) {
    __shared__ __attribute__((aligned(16))) unsigned short Kv[2][8192];  // 32KB K double-buffer
    __shared__ __attribute__((aligned(16))) unsigned short Vv[2][8192];  // 32KB V double-buffer
    const int idx = blockIdx.x;
    const int b = (idx & 7) * 2 + ((idx >> 3) & 1);   // XCD x holds batches {2x,2x+1} (4MB K/V = L2)
    const int rg = idx >> 4;                          // 0..31
    const int t = threadIdx.x, lane = t & 63, w = t >> 6;
    const int il = lane & 31, h = lane >> 5;
    const int iw = (rg * 4 + w) * 32;                 // this wave's 32 q-rows

    const unsigned short* Kb = Kf + ((size_t)b * 64) * 8192;
    const unsigned short* Vb = Vf + ((size_t)b * 64) * 8192;

    // prologue: stage K0 (slot 0), K1 (slot 1), V0 (slot 0)
    stage_tile(&Kv[0][0], Kb, t, w);
    stage_tile(&Kv[1][0], Kb + 8192, t, w);
    stage_tile(&Vv[0][0], Vb, t, w);

    bf16x8 qb[8];
    #pragma unroll
    for (int kc = 0; kc < 8; ++kc)
        qb[kc] = *(const bf16x8*)&qT[((size_t)b * NPOS + iw + il) * NC + kc * 16 + h * 8];

    bf16x8 ones;
    {
        u32x4 o; o[0] = o[1] = o[2] = o[3] = 0x3F803F80u;   // bf16 1.0 x8
        ones = __builtin_bit_cast(bf16x8, o);
    }
    f32x16 z16;
    #pragma unroll
    for (int q = 0; q < 16; ++q) z16[q] = 0.f;

    f32x16 acc[4], accl;
    #pragma unroll
    for (int ct = 0; ct < 4; ++ct)
        #pragma unroll
        for (int q = 0; q < 16; ++q) acc[ct][q] = 0.f;
    #pragma unroll
    for (int q = 0; q < 16; ++q) accl[q] = 0.f;

    __syncthreads();   // K0,K1,V0 staged (barrier drains vmcnt)

    // QK[0] (skewed out of the loop; z16 C-operand on first MFMA of each chain)
    f32x16 st[2];
    {
        const unsigned short* kl = &Kv[0][0] + lane * 8;
        __builtin_amdgcn_s_setprio(1);
        #pragma unroll
        for (int kc = 0; kc < 8; ++kc) {
            bf16x8 k0 = *(const bf16x8*)(kl + kc * 512);
            bf16x8 k1 = *(const bf16x8*)(kl + (8 + kc) * 512);
            st[0] = __builtin_amdgcn_mfma_f32_32x32x16_bf16(k0, qb[kc], kc ? st[0] : z16, 0, 0, 0);
            st[1] = __builtin_amdgcn_mfma_f32_32x32x16_bf16(k1, qb[kc], kc ? st[1] : z16, 0, 0, 0);
        }
        __builtin_amdgcn_s_setprio(0);
    }
    __syncthreads();   // all waves done reading Kv[0] before iter 0 stages K[2] into it

    // hot loop branch-free (stage K[jt+2] valid for jt<=61, V[jt+1] for jt<=62)
    for (int jt = 0; jt < 62; ++jt)
        flash_body<true, true, true, true>(jt, st, z16, qb, ones, acc, accl, Kv, Vv, Kb, Vb, t, w, lane);
    flash_body<false, true, true, true>(62, st, z16, qb, ones, acc, accl, Kv, Vv, Kb, Vb, t, w, lane);
    flash_body<false, false, false, false>(63, st, z16, qb, ones, acc, accl, Kv, Vv, Kb, Vb, t, w, lane);

    // ---- Epilogue: lr from accl (all C-rows equal -> lane-local, no shfl), normalize O,
    // B-frags, wf proj, +bias +x, store fp32
    const float lr = accl[0];
    bf16x8 obf[8];
    {
        float inv = __builtin_amdgcn_rcpf(lr) * 1.001953125f;  // centers O pkbf truncation
        #pragma unroll
        for (int ct = 0; ct < 4; ++ct) {
            float pp[16];
            #pragma unroll
            for (int q = 0; q < 16; ++q) pp[q] = acc[ct][q] * inv;
            mk_bfrag_pair(pp, &obf[ct * 2]);
        }
    }

    #pragma unroll
    for (int ot = 0; ot < 4; ++ot) {
        bf16x8 wfA[8];
        #pragma unroll
        for (int kc = 0; kc < 8; ++kc)
            wfA[kc] = *(const bf16x8*)&wfb[(ot * 32 + il) * 128 + kc * 16 + h * 8];
        f32x16 d;
        #pragma unroll
        for (int q = 0; q < 16; ++q) d[q] = 0.f;
        #pragma unroll
        for (int kc = 0; kc < 8; ++kc)
            d = __builtin_amdgcn_mfma_f32_32x32x16_bf16(wfA[kc], obf[kc], d, 0, 0, 0);
        const int gi = iw + il;
        #pragma unroll
        for (int q = 0; q < 16; ++q) {
            int o = ot * 32 + (q & 3) + 8 * (q >> 2) + 4 * h;
            size_t a = ((size_t)(b * NC + o)) * NPOS + gi;
            out[a] = d[q] + bf_[o] + x[a];
        }
    }
}

extern "C" void kernel_launch(void* const* d_in, const int* in_sizes, int n_in,
                              void* d_out, int out_size, void* d_ws, size_t ws_size,
                              hipStream_t stream) {
    const float* x   = (const float*)d_in[0];
    const float* gnw = (const float*)d_in[1];
    const float* gnb = (const float*)d_in[2];
    const float* wq  = (const float*)d_in[3];
    const float* bq  = (const float*)d_in[4];
    const float* wk  = (const float*)d_in[5];
    const float* bk  = (const float*)d_in[6];
    const float* wv  = (const float*)d_in[7];
    const float* bv  = (const float*)d_in[8];
    const float* wf  = (const float*)d_in[9];
    const float* bf_ = (const float*)d_in[10];
    float* out = (float*)d_out;

    char* ws = (char*)d_ws;
    float* mean = (float*)(ws + 0);
    float* rstd = (float*)(ws + 512);
    unsigned short* wqb = (unsigned short*)(ws + 1024);
    unsigned short* wkb = wqb + 16384;
    unsigned short* wvb = wkb + 16384;
    unsigned short* wfb = wvb + 16384;
    unsigned short* qT  = (unsigned short*)(ws + 132096);          // [b][n][c] bf16 (SCF-scaled)
    unsigned short* Kf  = qT + (size_t)NB * NPOS * NC;             // frag-linear K
    unsigned short* Vf  = Kf + (size_t)NB * NPOS * NC;             // frag-linear V

    gnstat_kernel<<<128, 256, 0, stream>>>(x, mean, rstd, wq, wk, wv, wf, wqb, wkb, wvb, wfb);
    dim3 g(64, 16);
    qkv_kernel<<<g, 256, 0, stream>>>(x, gnw, gnb, mean, rstd, wqb, wkb, wvb, bq, bk, bv, qT, Kf, Vf);
    flash_kernel<<<512, 256, 0, stream>>>(qT, Kf, Vf, wfb, bf_, x, out);
}

// Round 13
// 289.614 us; speedup vs baseline: 1.0292x; 1.0136x over previous
//
#include <hip/hip_runtime.h>

// Problem constants: b=16, c=128, groups=8, h=w=64 -> n=4096
#define NB   16
#define NC   128
#define NPOS 4096

typedef short bf16x8 __attribute__((ext_vector_type(8)));   // 8 bf16 (4 VGPRs)
typedef float f32x4  __attribute__((ext_vector_type(4)));
typedef float f32x16 __attribute__((ext_vector_type(16)));
typedef unsigned int u32x4 __attribute__((ext_vector_type(4)));
typedef unsigned int u32x2 __attribute__((ext_vector_type(2)));

// softmax scale folded into q at QKV time: log2(e)/sqrt(128)
#define SCF 0.12751743075095855f

static __device__ __forceinline__ unsigned short f2bf(float f) {
    unsigned int u = __builtin_bit_cast(unsigned int, f);
    u += 0x7FFFu + ((u >> 16) & 1u);   // round-to-nearest-even
    return (unsigned short)(u >> 16);
}

// pack two floats -> bf16x2 dword (truncating; self-consistent softmax ratio cancels scale)
static __device__ __forceinline__ unsigned int pkbf(float hi, float lo) {
    return __builtin_amdgcn_perm(__builtin_bit_cast(unsigned int, hi),
                                 __builtin_bit_cast(unsigned int, lo), 0x07060302u);
}

// Build two B-operand frags (chunk parity 0/1) from 16 per-lane floats in C-layout.
// T12: v_permlane32_swap(A,B) -> {[A_lo|B_lo],[A_hi|B_hi]} (HW-verified R9).
static __device__ __forceinline__ void mk_bfrag_pair(const float* pp, bf16x8* dst) {
    #pragma unroll
    for (int c2 = 0; c2 < 2; ++c2) {
        int rb = c2 * 8;
        unsigned int A0 = pkbf(pp[rb + 1], pp[rb + 0]);
        unsigned int A1 = pkbf(pp[rb + 3], pp[rb + 2]);
        unsigned int B0 = pkbf(pp[rb + 5], pp[rb + 4]);
        unsigned int B1 = pkbf(pp[rb + 7], pp[rb + 6]);
        u32x2 r0 = __builtin_amdgcn_permlane32_swap(A0, B0, false, false);
        u32x2 r1 = __builtin_amdgcn_permlane32_swap(A1, B1, false, false);
        u32x4 f;
        f[0] = r0[0]; f[1] = r1[0]; f[2] = r0[1]; f[3] = r1[1];
        dst[c2] = __builtin_bit_cast(bf16x8, f);
    }
}

// Stage one 16KB frag-linear tile (8192 bf16) global -> LDS, 256 threads cooperative.
static __device__ __forceinline__ void stage_tile(unsigned short* lds, const unsigned short* g,
                                                  int t, int w) {
    #pragma unroll
    for (int c = 0; c < 4; ++c) {
        __builtin_amdgcn_global_load_lds(
            (const __attribute__((address_space(1))) unsigned int*)(g + c * 2048 + t * 8),
            (__attribute__((address_space(3))) unsigned int*)(lds + c * 2048 + w * 512),
            16, 0, 0);
    }
}

// ---------------- K1: GroupNorm stats + fused weight fp32->bf16 conversion ----------------
__global__ void gnstat_kernel(const float* __restrict__ x, float* __restrict__ mean,
                              float* __restrict__ rstd,
                              const float* __restrict__ wq, const float* __restrict__ wk,
                              const float* __restrict__ wv, const float* __restrict__ wf,
                              unsigned short* __restrict__ oq, unsigned short* __restrict__ ok,
                              unsigned short* __restrict__ ov, unsigned short* __restrict__ of) {
    int bg = blockIdx.x;
    int t = threadIdx.x;
    {
        int e2 = (bg * 256 + t) * 2;
        int m = e2 >> 14, e = e2 & 16383;
        const float* W = m == 0 ? wq : m == 1 ? wk : m == 2 ? wv : wf;
        unsigned short* O = m == 0 ? oq : m == 1 ? ok : m == 2 ? ov : of;
        float2 v = *(const float2*)&W[e];
        O[e] = f2bf(v.x); O[e + 1] = f2bf(v.y);
    }
    const float* p = x + (size_t)bg * 65536;
    float s = 0.f, q = 0.f;
    for (int it = 0; it < 64; ++it) {
        f32x4 v = *(const f32x4*)(p + it * 1024 + t * 4);
        s += v[0] + v[1] + v[2] + v[3];
        q += v[0] * v[0] + v[1] * v[1] + v[2] * v[2] + v[3] * v[3];
    }
    for (int m = 1; m < 64; m <<= 1) { s += __shfl_xor(s, m); q += __shfl_xor(q, m); }
    __shared__ float ls[4], lq[4];
    int w = t >> 6;
    if ((t & 63) == 0) { ls[w] = s; lq[w] = q; }
    __syncthreads();
    if (t == 0) {
        s = ls[0] + ls[1] + ls[2] + ls[3];
        q = lq[0] + lq[1] + lq[2] + lq[3];
        float mu  = s * (1.0f / 65536.0f);
        float var = q * (1.0f / 65536.0f) - mu * mu;
        mean[bg] = mu;
        rstd[bg] = rsqrtf(var + 1e-5f);
    }
}

// ---------------- K2: GN-apply + QKV GEMMs (grid 64 x 16, 256 thr) ----------------
__global__ __launch_bounds__(256) void qkv_kernel(
    const float* __restrict__ x, const float* __restrict__ gnw, const float* __restrict__ gnb,
    const float* __restrict__ mean, const float* __restrict__ rstd,
    const unsigned short* __restrict__ wqb, const unsigned short* __restrict__ wkb,
    const unsigned short* __restrict__ wvb,
    const float* __restrict__ bq, const float* __restrict__ bk, const float* __restrict__ bv,
    unsigned short* __restrict__ qT, unsigned short* __restrict__ Kf, unsigned short* __restrict__ Vf) {
    __shared__ __attribute__((aligned(16))) unsigned short xn[64 * 136];  // [i][c], stride 136
    __shared__ __attribute__((aligned(16))) unsigned short bnc[64 * 128]; // bounce (8192 elems)
    const int b = blockIdx.y, i0 = blockIdx.x * 64, jt = blockIdx.x;
    const int t = threadIdx.x;
    {
        int iL = (t & 15) * 4;
        int cb = (t >> 4) * 2;
        for (int cg = 0; cg < 4; ++cg) {
            int c = cg * 32 + cb;
            int g = c >> 4;
            float mu = mean[b * 8 + g], rs = rstd[b * 8 + g];
            float ga0 = gnw[c] * rs,     be0 = gnb[c]     - mu * ga0;
            float ga1 = gnw[c + 1] * rs, be1 = gnb[c + 1] - mu * ga1;
            const float* p0 = x + ((size_t)(b * NC + c)) * NPOS + i0 + iL;
            f32x4 v0 = *(const f32x4*)p0;
            f32x4 v1 = *(const f32x4*)(p0 + NPOS);
            for (int e = 0; e < 4; ++e) {
                unsigned int u = (unsigned)f2bf(v0[e] * ga0 + be0) |
                                 ((unsigned)f2bf(v1[e] * ga1 + be1) << 16);
                *(unsigned int*)&xn[(iL + e) * 136 + c] = u;
            }
        }
    }
    __syncthreads();

    const int lane = t & 63, w = t >> 6, quad = lane >> 4, li = lane & 15;

    bf16x8 ax[4];
    for (int kc = 0; kc < 4; ++kc)
        ax[kc] = *(const bf16x8*)&xn[(w * 16 + li) * 136 + kc * 32 + quad * 8];

    // ---- q and k GEMMs; D[i][o], i = w*16+quad*4+rr, o = nt*16+li
    for (int wt = 0; wt < 2; ++wt) {
        const unsigned short* W = wt ? wkb : wqb;
        const float* bias = wt ? bk : bq;
        const float osc = wt ? 1.0f : SCF;
        for (int nt = 0; nt < 8; ++nt) {
            f32x4 d = {0.f, 0.f, 0.f, 0.f};
            for (int kc = 0; kc < 4; ++kc) {
                bf16x8 bw = *(const bf16x8*)&W[(nt * 16 + li) * 128 + kc * 32 + quad * 8];
                d = __builtin_amdgcn_mfma_f32_16x16x32_bf16(ax[kc], bw, d, 0, 0, 0);
            }
            float bb = bias[nt * 16 + li];
            int o = nt * 16 + li;
            for (int rr = 0; rr < 4; ++rr) {
                int i = w * 16 + quad * 4 + rr;
                bnc[i * 128 + (((o >> 3) ^ (i & 7)) << 3) + (o & 7)] = f2bf((d[rr] + bb) * osc);
            }
        }
        __syncthreads();
        if (wt == 0) {
            unsigned short* dst = qT + ((size_t)b * NPOS + i0) * NC + t * 32;
            int i = t >> 2;
            for (int s = 0; s < 4; ++s) {
                int cc = (t & 3) * 4 + s;
                *(bf16x8*)(dst + s * 8) = *(const bf16x8*)&bnc[i * 128 + ((cc ^ (i & 7)) << 3)];
            }
        } else {
            unsigned short* dst = Kf + ((size_t)(b * 64 + jt)) * 8192 + t * 32;
            int F = t >> 4, jtile = F >> 3, kc = F & 7;
            for (int s = 0; s < 4; ++s) {
                int L = (t * 4 + s) & 63;
                int i = jtile * 32 + (L & 31);
                int cc = kc * 2 + (L >> 5);
                *(bf16x8*)(dst + s * 8) = *(const bf16x8*)&bnc[i * 128 + ((cc ^ (i & 7)) << 3)];
            }
        }
        __syncthreads();
    }

    // ---- v GEMM: D[o=c][i=j], c = (w*2+mt)*16+quad*4+rr, j = nt*16+li
    bf16x8 av[2][4];
    for (int mt = 0; mt < 2; ++mt)
        for (int kc = 0; kc < 4; ++kc)
            av[mt][kc] = *(const bf16x8*)&wvb[((w * 2 + mt) * 16 + li) * 128 + kc * 32 + quad * 8];
    for (int nt = 0; nt < 4; ++nt) {
        bf16x8 bx[4];
        for (int kc = 0; kc < 4; ++kc)
            bx[kc] = *(const bf16x8*)&xn[(nt * 16 + li) * 136 + kc * 32 + quad * 8];
        for (int mt = 0; mt < 2; ++mt) {
            f32x4 d = {0.f, 0.f, 0.f, 0.f};
            for (int kc = 0; kc < 4; ++kc)
                d = __builtin_amdgcn_mfma_f32_16x16x32_bf16(av[mt][kc], bx[kc], d, 0, 0, 0);
            int o0 = (w * 2 + mt) * 16 + quad * 4;
            int j = nt * 16 + li;
            for (int rr = 0; rr < 4; ++rr) {
                int c = o0 + rr;
                bnc[c * 64 + (((j >> 3) ^ (c & 7)) << 3) + (j & 7)] = f2bf(d[rr] + bv[c]);
            }
        }
    }
    __syncthreads();
    {
        unsigned short* dst = Vf + ((size_t)(b * 64 + jt)) * 8192 + t * 32;
        int F = t >> 4, ct = F >> 2, kc2 = F & 3;
        for (int s = 0; s < 4; ++s) {
            int L = (t * 4 + s) & 63;
            int c = ct * 32 + (L & 31);
            int jc = kc2 * 2 + (L >> 5);
            *(bf16x8*)(dst + s * 8) = *(const bf16x8*)&bnc[c * 64 + ((jc ^ (c & 7)) << 3)];
        }
    }
}

// ---------------- flash iteration body (st double-buffered: stC current, stN next) ----------------
// R13 vs R12: PHASE 1 hand-interleaves QK(t+1) MFMAs (into stN) 1:2 with the exp2 chain of
// softmax(t) (on stC) — they are fully independent, so the wave issues MFMA then 2 exp2s
// while the matrix pipe chews (~8 cyc/MFMA). Removes the strict [VALU phase][MFMA phase]
// alternation that left every pipe <50% busy in R9-R12. PHASE 2 = PV + ones-rowsum cluster
// (R12's proven arithmetic: no centering, self-consistent lr, lane-local epilogue).
template<bool SK, bool SV, bool DOQK, bool BAR>
static __device__ __forceinline__ void flash_body(
    int jt, f32x16 (&stC)[2], f32x16 (&stN)[2], const f32x16& z16,
    const bf16x8 (&qb)[8], const bf16x8& ones,
    f32x16 (&acc)[4], f32x16& accl,
    unsigned short (*Kv)[8192], unsigned short (*Vv)[8192],
    const unsigned short* Kb, const unsigned short* Vb, int t, int w, int lane) {
    // staging issues first: lands by this iter's end barrier.
    if (SK) stage_tile(&Kv[jt & 1][0], Kb + (size_t)(jt + 2) * 8192, t, w);
    if (SV) stage_tile(&Vv[(jt + 1) & 1][0], Vb + (size_t)(jt + 1) * 8192, t, w);

    const unsigned short* vl = &Vv[jt & 1][0] + lane * 8;
    const unsigned short* kl = &Kv[(jt + 1) & 1][0] + lane * 8;

    // PHASE 1: QK(t+1) MFMAs interleaved with softmax(t) exp2 (independent chains;
    // QK starts from z16 C-operand on each chain's first MFMA).
    __builtin_amdgcn_s_setprio(1);
    #pragma unroll
    for (int i = 0; i < 16; ++i) {
        if (DOQK) {
            const int ch = i & 1, kc = i >> 1;
            bf16x8 kx = *(const bf16x8*)(kl + (ch * 8 + kc) * 512);
            stN[ch] = __builtin_amdgcn_mfma_f32_32x32x16_bf16(kx, qb[kc],
                                                              (i < 2) ? z16 : stN[ch], 0, 0, 0);
        }
        stC[0][i] = __builtin_amdgcn_exp2f(stC[0][i]);
        stC[1][i] = __builtin_amdgcn_exp2f(stC[1][i]);
    }
    __builtin_amdgcn_s_setprio(0);

    bf16x8 pfrag[4];
    mk_bfrag_pair((const float*)&stC[0], &pfrag[0]);
    mk_bfrag_pair((const float*)&stC[1], &pfrag[2]);

    // PHASE 2: PV(t) cluster + ones-MFMA rowsum (4 per iter) on the matrix pipe.
    __builtin_amdgcn_s_setprio(1);
    #pragma unroll
    for (int i = 0; i < 16; ++i) {
        const int ct = i & 3, kc2 = i >> 2;
        bf16x8 vfm = *(const bf16x8*)(vl + (ct * 4 + kc2) * 512);
        acc[ct] = __builtin_amdgcn_mfma_f32_32x32x16_bf16(vfm, pfrag[kc2], acc[ct], 0, 0, 0);
        if ((i & 3) == 3)
            accl = __builtin_amdgcn_mfma_f32_32x32x16_bf16(ones, pfrag[i >> 2], accl, 0, 0, 0);
    }
    __builtin_amdgcn_s_setprio(0);

    // barrier: all waves done reading Kv[(jt+1)&1]/Vv[jt&1]; drains vmcnt so staged
    // K[jt+2]/V[jt+1] are complete for the next iteration's reads.
    if (BAR) __syncthreads();
}

// ---------------- K3: flash attention + fused output projection + residual ----------------
// grid 512 x 256 thr = 4 waves/block, 32 q-rows/wave, 2 blocks/CU, 2 waves/SIMD (proven
// optimum: 64-row waves cap at 1 wave/SIMD and lost twice R5/R10; rowsum-on-VALU lost R11).
__global__ __launch_bounds__(256, 2) void flash_kernel(
    const unsigned short* __restrict__ qT, const unsigned short* __restrict__ Kf,
    const unsigned short* __restrict__ Vf, const unsigned short* __restrict__ wfb,
    const float* __restrict__ bf_, const float* __restrict__ x, float* __restrict__ out) {
    __shared__ __attribute__((aligned(16))) unsigned short Kv[2][8192];  // 32KB K double-buffer
    __shared__ __attribute__((aligned(16))) unsigned short Vv[2][8192];  // 32KB V double-buffer
    const int idx = blockIdx.x;
    const int b = (idx & 7) * 2 + ((idx >> 3) & 1);   // XCD x holds batches {2x,2x+1} (4MB K/V = L2)
    const int rg = idx >> 4;                          // 0..31
    const int t = threadIdx.x, lane = t & 63, w = t >> 6;
    const int il = lane & 31, h = lane >> 5;
    const int iw = (rg * 4 + w) * 32;                 // this wave's 32 q-rows

    const unsigned short* Kb = Kf + ((size_t)b * 64) * 8192;
    const unsigned short* Vb = Vf + ((size_t)b * 64) * 8192;

    // prologue: stage K0 (slot 0), K1 (slot 1), V0 (slot 0)
    stage_tile(&Kv[0][0], Kb, t, w);
    stage_tile(&Kv[1][0], Kb + 8192, t, w);
    stage_tile(&Vv[0][0], Vb, t, w);

    bf16x8 qb[8];
    #pragma unroll
    for (int kc = 0; kc < 8; ++kc)
        qb[kc] = *(const bf16x8*)&qT[((size_t)b * NPOS + iw + il) * NC + kc * 16 + h * 8];

    bf16x8 ones;
    {
        u32x4 o; o[0] = o[1] = o[2] = o[3] = 0x3F803F80u;   // bf16 1.0 x8
        ones = __builtin_bit_cast(bf16x8, o);
    }
    f32x16 z16;
    #pragma unroll
    for (int q = 0; q < 16; ++q) z16[q] = 0.f;

    f32x16 acc[4], accl;
    #pragma unroll
    for (int ct = 0; ct < 4; ++ct)
        #pragma unroll
        for (int q = 0; q < 16; ++q) acc[ct][q] = 0.f;
    #pragma unroll
    for (int q = 0; q < 16; ++q) accl[q] = 0.f;

    __syncthreads();   // K0,K1,V0 staged (barrier drains vmcnt)

    // QK[0] -> stA (skewed out of the loop; z16 C-operand on first MFMA of each chain)
    f32x16 stA[2], stB[2];
    {
        const unsigned short* kl = &Kv[0][0] + lane * 8;
        __builtin_amdgcn_s_setprio(1);
        #pragma unroll
        for (int kc = 0; kc < 8; ++kc) {
            bf16x8 k0 = *(const bf16x8*)(kl + kc * 512);
            bf16x8 k1 = *(const bf16x8*)(kl + (8 + kc) * 512);
            stA[0] = __builtin_amdgcn_mfma_f32_32x32x16_bf16(k0, qb[kc], kc ? stA[0] : z16, 0, 0, 0);
            stA[1] = __builtin_amdgcn_mfma_f32_32x32x16_bf16(k1, qb[kc], kc ? stA[1] : z16, 0, 0, 0);
        }
        __builtin_amdgcn_s_setprio(0);
    }
    __syncthreads();   // all waves done reading Kv[0] before iter 0 stages K[2] into it

    // ping-pong stC/stN, unrolled x2; peel 62 (no K stage) and 63 (no stage/QK/barrier)
    for (int jo = 0; jo < 31; ++jo) {
        flash_body<true, true, true, true>(2 * jo,     stA, stB, z16, qb, ones, acc, accl, Kv, Vv, Kb, Vb, t, w, lane);
        flash_body<true, true, true, true>(2 * jo + 1, stB, stA, z16, qb, ones, acc, accl, Kv, Vv, Kb, Vb, t, w, lane);
    }
    flash_body<false, true, true, true>(62, stA, stB, z16, qb, ones, acc, accl, Kv, Vv, Kb, Vb, t, w, lane);
    flash_body<false, false, false, false>(63, stB, stA, z16, qb, ones, acc, accl, Kv, Vv, Kb, Vb, t, w, lane);

    // ---- Epilogue: lr from accl (all C-rows equal -> lane-local, no shfl), normalize O,
    // B-frags, wf proj, +bias +x, store fp32
    const float lr = accl[0];
    bf16x8 obf[8];
    {
        float inv = __builtin_amdgcn_rcpf(lr) * 1.001953125f;  // centers O pkbf truncation
        #pragma unroll
        for (int ct = 0; ct < 4; ++ct) {
            float pp[16];
            #pragma unroll
            for (int q = 0; q < 16; ++q) pp[q] = acc[ct][q] * inv;
            mk_bfrag_pair(pp, &obf[ct * 2]);
        }
    }

    #pragma unroll
    for (int ot = 0; ot < 4; ++ot) {
        bf16x8 wfA[8];
        #pragma unroll
        for (int kc = 0; kc < 8; ++kc)
            wfA[kc] = *(const bf16x8*)&wfb[(ot * 32 + il) * 128 + kc * 16 + h * 8];
        f32x16 d;
        #pragma unroll
        for (int q = 0; q < 16; ++q) d[q] = 0.f;
        #pragma unroll
        for (int kc = 0; kc < 8; ++kc)
            d = __builtin_amdgcn_mfma_f32_32x32x16_bf16(wfA[kc], obf[kc], d, 0, 0, 0);
        const int gi = iw + il;
        #pragma unroll
        for (int q = 0; q < 16; ++q) {
            int o = ot * 32 + (q & 3) + 8 * (q >> 2) + 4 * h;
            size_t a = ((size_t)(b * NC + o)) * NPOS + gi;
            out[a] = d[q] + bf_[o] + x[a];
        }
    }
}

extern "C" void kernel_launch(void* const* d_in, const int* in_sizes, int n_in,
                              void* d_out, int out_size, void* d_ws, size_t ws_size,
                              hipStream_t stream) {
    const float* x   = (const float*)d_in[0];
    const float* gnw = (const float*)d_in[1];
    const float* gnb = (const float*)d_in[2];
    const float* wq  = (const float*)d_in[3];
    const float* bq  = (const float*)d_in[4];
    const float* wk  = (const float*)d_in[5];
    const float* bk  = (const float*)d_in[6];
    const float* wv  = (const float*)d_in[7];
    const float* bv  = (const float*)d_in[8];
    const float* wf  = (const float*)d_in[9];
    const float* bf_ = (const float*)d_in[10];
    float* out = (float*)d_out;

    char* ws = (char*)d_ws;
    float* mean = (float*)(ws + 0);
    float* rstd = (float*)(ws + 512);
    unsigned short* wqb = (unsigned short*)(ws + 1024);
    unsigned short* wkb = wqb + 16384;
    unsigned short* wvb = wkb + 16384;
    unsigned short* wfb = wvb + 16384;
    unsigned short* qT  = (unsigned short*)(ws + 132096);          // [b][n][c] bf16 (SCF-scaled)
    unsigned short* Kf  = qT + (size_t)NB * NPOS * NC;             // frag-linear K
    unsigned short* Vf  = Kf + (size_t)NB * NPOS * NC;             // frag-linear V

    gnstat_kernel<<<128, 256, 0, stream>>>(x, mean, rstd, wq, wk, wv, wf, wqb, wkb, wvb, wfb);
    dim3 g(64, 16);
    qkv_kernel<<<g, 256, 0, stream>>>(x, gnw, gnb, mean, rstd, wqb, wkb, wvb, bq, bk, bv, qT, Kf, Vf);
    flash_kernel<<<512, 256, 0, stream>>>(qT, Kf, Vf, wfb, bf_, x, out);
}